// Round 9
// baseline (124.780 us; speedup 1.0000x reference)
//
#include <hip/hip_runtime.h>
#include <stdint.h>

#define BATCH      8
#define CDIM       32
#define KLBL       64
#define NPB        200000          // n per batch (6250 slabs * 32)
#define SLABS      6250
#define NCHUNK     32              // grid = 32 chunks x 2 c-halves x 8 b = 512
#define NBLOCKS    (NCHUNK * 2 * BATCH)
#define TILE_SLABS 32              // 1024 n per tile
#define ROWB       4096            // LDS bytes per row (1024 f32)

typedef __attribute__((ext_vector_type(8))) short bf16x8;
typedef __attribute__((ext_vector_type(4))) float f32x4;
union ABits { uint32_t u[4]; bf16x8 v; };

__device__ __forceinline__ uint32_t cvtpk_bf16(float lo, float hi) {
  uint32_t r;
  asm volatile("v_cvt_pk_bf16_f32 %0, %1, %2" : "=v"(r) : "v"(lo), "v"(hi));
  return r;
}
__device__ __forceinline__ void stage16(const void* g, void* l) {
  __builtin_amdgcn_global_load_lds(
      (const __attribute__((address_space(1))) void*)(uintptr_t)g,
      (__attribute__((address_space(3))) void*)(uintptr_t)l, 16, 0, 0);
}
__device__ __forceinline__ float agent_ld(const float* p) {
  return __hip_atomic_load(p, __ATOMIC_RELAXED, __HIP_MEMORY_SCOPE_AGENT);
}

// ---- single fused kernel: gather+MFMA segment sums, flush, loss tail ----
__global__ __launch_bounds__(256, 2) void seg_fused_kernel(
    const float* __restrict__ pred,     // [B][C][N] f32
    const int*   __restrict__ label,    // [B][N] i32
    float* __restrict__ gsums,          // [B][K][C] (memset 0 per call)
    float* __restrict__ gcounts,        // [B][K]    (memset 0 per call)
    uint32_t* __restrict__ counter,     // 1 u32    (memset 0 per call)
    float* __restrict__ out) {          // scalar, written by last block only
  __shared__ __align__(16) uint8_t smem[16 * ROWB + 4096];  // 68KB tile+labels
  __shared__ uint32_t s_last;
  __shared__ float s_total;
  uint8_t* tile = smem;
  uint8_t* labl = smem + 16 * ROWB;

  const int tid = threadIdx.x, wv = tid >> 6, ln = tid & 63;
  const int chunk = blockIdx.x, chalf = blockIdx.y, b = blockIdx.z;
  const int crow = ln & 15, g = ln >> 4;

  const int s0 = chunk * SLABS / NCHUNK;
  const int s1 = (chunk + 1) * SLABS / NCHUNK;
  const int T = (s1 - s0 + TILE_SLABS - 1) / TILE_SLABS;

  ABits ones_;
  ones_.u[0] = ones_.u[1] = ones_.u[2] = ones_.u[3] = 0x3F803F80u;

  f32x4 acc[4], cnt[4];   // indexed only by unrolled kt
#pragma unroll
  for (int kt = 0; kt < 4; ++kt) {
    acc[kt] = (f32x4){0.f, 0.f, 0.f, 0.f};
    cnt[kt] = (f32x4){0.f, 0.f, 0.f, 0.f};
  }

  // wave's 4 staging rows
  const float* prow[4];
#pragma unroll
  for (int j = 0; j < 4; ++j)
    prow[j] = pred + ((size_t)b * CDIM + chalf * 16 + wv * 4 + j) * NPB;
  const int* labp = label + (size_t)b * NPB;

#define SLAB_BODY(CNT_)                                                        \
  do {                                                                         \
    const int4 la  = *(const int4*)(labl + ss * 128 + g * 32);                 \
    const int4 lb2 = *(const int4*)(labl + ss * 128 + g * 32 + 16);            \
    const int u = ss * 8 + g * 2, sx = crow & 7;                               \
    const f32x4 lo = *(const f32x4*)(tile + crow * ROWB + ((u ^ sx) << 4));    \
    const f32x4 hi = *(const f32x4*)(tile + crow * ROWB + (((u + 1) ^ sx) << 4)); \
    ABits bfr;                                                                 \
    bfr.u[0] = cvtpk_bf16(lo.x, lo.y);                                         \
    bfr.u[1] = cvtpk_bf16(lo.z, lo.w);                                         \
    bfr.u[2] = cvtpk_bf16(hi.x, hi.y);                                         \
    bfr.u[3] = cvtpk_bf16(hi.z, hi.w);                                         \
    _Pragma("unroll")                                                          \
    for (int kt = 0; kt < 4; ++kt) {                                           \
      const int tgt = kt * 16 + crow;                                          \
      ABits a;                                                                 \
      a.u[0] = (la.x == tgt ? 0x3F80u : 0u) | (la.y == tgt ? 0x3F800000u : 0u);\
      a.u[1] = (la.z == tgt ? 0x3F80u : 0u) | (la.w == tgt ? 0x3F800000u : 0u);\
      a.u[2] = (lb2.x == tgt ? 0x3F80u : 0u) | (lb2.y == tgt ? 0x3F800000u : 0u);\
      a.u[3] = (lb2.z == tgt ? 0x3F80u : 0u) | (lb2.w == tgt ? 0x3F800000u : 0u);\
      acc[kt] = __builtin_amdgcn_mfma_f32_16x16x32_bf16(a.v, bfr.v, acc[kt], 0, 0, 0); \
      if (CNT_) cnt[kt] = __builtin_amdgcn_mfma_f32_16x16x32_bf16(a.v, ones_.v, cnt[kt], 0, 0, 0); \
    }                                                                          \
  } while (0)

  for (int t = 0; t < T; ++t) {
    const int tn0 = (s0 + t * TILE_SLABS) * 32;
    const int ns = min(TILE_SLABS, s1 - s0 - t * TILE_SLABS);
    const int nq = (ns + 7) >> 3;   // 1KB calls per row (8 slabs per call)

    // ---- stage: 4KB-contiguous runs per row, pre-swizzled source ----
#pragma unroll
    for (int j = 0; j < 4; ++j) {
      const int r = wv * 4 + j, sx = r & 7;
      for (int q = 0; q < nq; ++q) {
        int n0 = tn0 + q * 256;
        if (n0 > NPB - 256) n0 = NPB - 256;
        stage16(prow[j] + n0 + ((ln ^ sx) << 2), tile + r * ROWB + q * 1024);
      }
    }
    if (wv == 3)
      for (int q = 0; q < nq; ++q) {
        int n0 = tn0 + q * 256;
        if (n0 > NPB - 256) n0 = NPB - 256;
        stage16(labp + n0 + (ln << 2), labl + q * 1024);
      }
    __syncthreads();   // vmcnt(0)+lgkmcnt(0) drain + barrier: tile ready

    // ---- consume: waves split slabs (stride 4) ----
    if (chalf == 0) {
      for (int ss = wv; ss < ns; ss += 4) SLAB_BODY(true);
    } else {
      for (int ss = wv; ss < ns; ss += 4) SLAB_BODY(false);
    }
    __syncthreads();   // all consumed: buffer reusable
  }

  // ---- flush: 4-wave LDS reduce (alias tile), then global atomics ----
  float* sp = (float*)smem;   // [4][1088]
#pragma unroll
  for (int kt = 0; kt < 4; ++kt)
#pragma unroll
    for (int r = 0; r < 4; ++r) {
      const int k = kt * 16 + g * 4 + r;   // D: col=ln&15, row=(ln>>4)*4+r
      sp[wv * 1088 + k * 16 + crow] = acc[kt][r];
      if (chalf == 0 && crow == 0) sp[wv * 1088 + 1024 + k] = cnt[kt][r];
    }
  __syncthreads();

  float* gs = gsums + (size_t)b * (KLBL * CDIM);
  for (int i = tid; i < 1024; i += 256) {
    const float v = sp[i] + sp[1088 + i] + sp[2176 + i] + sp[3264 + i];
    atomicAdd(&gs[(i >> 4) * 32 + chalf * 16 + (i & 15)], v);
  }
  if (chalf == 0 && tid < 64) {
    const float v = sp[1024 + tid] + sp[2112 + tid] + sp[3200 + tid] + sp[4288 + tid];
    atomicAdd(&gcounts[b * 64 + tid], v);
  }

  // ---- completion: last block computes the loss ----
  __syncthreads();   // drains the atomics (vmcnt) before signaling
  if (tid == 0) {
    __threadfence();
    s_last = (__hip_atomic_fetch_add(counter, 1u, __ATOMIC_ACQ_REL,
                                     __HIP_MEMORY_SCOPE_AGENT) == NBLOCKS - 1);
    s_total = 0.f;
  }
  __syncthreads();
  if (!s_last) return;
  __threadfence();

  float* cen = (float*)smem;       // 2048
  float* red = cen + 2048;         // 256
  float* cb  = red + 256;          // 64
  for (int bb = 0; bb < BATCH; ++bb) {
    if (tid < 64) cb[tid] = fmaxf(agent_ld(gcounts + bb * 64 + tid), 1.0f);
    __syncthreads();
    for (int i = tid; i < 2048; i += 256)
      cen[i] = agent_ld(gsums + (size_t)bb * 2048 + i) / cb[i >> 5];
    __syncthreads();
    float a2 = 0.f;
    for (int p = tid; p < 1024; p += 256) {
      const int i = p >> 5, j = p & 31;
      float gr = 0.f, ni = 0.f, nj = 0.f;
#pragma unroll
      for (int k = 0; k < KLBL; ++k) {
        const float ci = cen[k * 32 + i];
        const float cj = cen[k * 32 + j];
        gr += ci * cj;
        ni += ci * ci;
        nj += cj * cj;
      }
      float sq = fmaxf(ni + nj - 2.f * gr, 0.f);
      const float dist = (sq > 0.f) ? sqrtf(sq) : 0.f;
      const float h = fmaxf(3.0f - dist, 0.f);   // 2*D_DIST = 3.0
      a2 += h * h;
    }
    red[tid] = a2;
    __syncthreads();
    for (int s2 = 128; s2 > 0; s2 >>= 1) {
      if (tid < s2) red[tid] += red[tid + s2];
      __syncthreads();
    }
    if (tid == 0) s_total += red[0];
    __syncthreads();
  }
  if (tid == 0)
    out[0] = s_total / (2.0f * (float)KLBL * ((float)KLBL - 1.0f));
}

// ---------------- launch: 1 memset + 1 kernel ----------------
extern "C" void kernel_launch(void* const* d_in, const int* in_sizes, int n_in,
                              void* d_out, int out_size, void* d_ws, size_t ws_size,
                              hipStream_t stream) {
  const float* pred  = (const float*)d_in[0];
  const int*   label = (const int*)d_in[1];

  float* gsums   = (float*)d_ws;                               // 16384 f32
  float* gcounts = gsums + (size_t)BATCH * KLBL * CDIM;        // 512 f32
  uint32_t* counter = (uint32_t*)(gcounts + BATCH * KLBL);     // 1 u32

  hipMemsetAsync(d_ws, 0, (size_t)(BATCH * KLBL * CDIM + BATCH * KLBL + 1) * 4,
                 stream);

  dim3 grid(NCHUNK, 2, BATCH);
  seg_fused_kernel<<<grid, 256, 0, stream>>>(pred, label, gsums, gcounts,
                                             counter, (float*)d_out);
}

// Round 10
// 70.764 us; speedup vs baseline: 1.7633x; 1.7633x over previous
//
#include <hip/hip_runtime.h>
#include <stdint.h>

#define BATCH   8
#define CDIM    32
#define KLBL    64
#define NPB     200000               // n per batch (6250 * 32)
#define SLABS   6250                 // 32-n slabs per batch
#define CHUNKS  64                   // 64*8 = 512 blocks = exactly 2 per CU
#define REC     (KLBL * CDIM + KLBL) // 2112 floats per partial record

typedef __attribute__((ext_vector_type(8))) short bf16x8;
typedef __attribute__((ext_vector_type(4))) float f32x4;

union ABits { uint32_t u[4]; bf16x8 v; };

__device__ __forceinline__ uint32_t cvtpk_bf16(float lo, float hi) {
  uint32_t r;
  asm volatile("v_cvt_pk_bf16_f32 %0, %1, %2" : "=v"(r) : "v"(lo), "v"(hi));
  return r;
}

// ---------------- Kernel 1: barrier-free one-hot MFMA segment sums --------
// grid = (CHUNKS, BATCH), block = 256 (4 waves). Each WAVE owns an exclusive
// n-range; computes the full 64k x 32c partial via 12 MFMA per 32-n slab.
// B-fragment loaded straight from global (lane ln&15 = channel row, 8
// consecutive n at (ln>>4)*8) + cvt_pk. Depth-2 named-set register prefetch,
// no barriers in the main loop. Flush = LDS wave-reduce -> partial record
// (plain coalesced stores; no global atomics, no workspace memset needed).
__global__ __launch_bounds__(256) void seg_mfma_kernel(
    const float* __restrict__ pred,     // [B][C][N] f32
    const int*   __restrict__ label,    // [B][N] i32
    float* __restrict__ partial,        // [B][CHUNKS][REC] fully overwritten
    float* __restrict__ out) {          // scalar; zeroed by block (0,0)
  __shared__ float s_part[4][REC];      // 33.8KB flush buffer

  const int tid = threadIdx.x;
  const int wv = tid >> 6;
  const int ln = tid & 63;
  const int chunk = blockIdx.x, b = blockIdx.y;

  if (chunk == 0 && b == 0 && tid == 0) out[0] = 0.f;  // loss runs after seg

  const int s0 = (int)((long long)chunk * SLABS / CHUNKS);
  const int s1 = (int)((long long)(chunk + 1) * SLABS / CHUNKS);
  const int w0 = s0 + (int)((long long)(s1 - s0) * wv / 4);
  const int w1 = s0 + (int)((long long)(s1 - s0) * (wv + 1) / 4);

  const int crow = ln & 15;          // channel row (and A label-row)
  const int kseg = (ln >> 4) * 8;    // n sub-offset within slab

  const float* row0 = pred + ((size_t)b * CDIM + crow) * NPB;       // c-lo
  const float* row1 = pred + ((size_t)b * CDIM + crow + 16) * NPB;  // c-hi
  const int*   labp = label + (size_t)b * NPB;

  ABits ones;
  ones.u[0] = ones.u[1] = ones.u[2] = ones.u[3] = 0x3F803F80u;

  f32x4 acc[4][2];   // [k-tile][c-tile], compile-time indices only
  f32x4 accc[4];     // counts per k-tile
#pragma unroll
  for (int kt = 0; kt < 4; ++kt) {
    acc[kt][0] = (f32x4){0.f, 0.f, 0.f, 0.f};
    acc[kt][1] = (f32x4){0.f, 0.f, 0.f, 0.f};
    accc[kt]   = (f32x4){0.f, 0.f, 0.f, 0.f};
  }

  // two named prefetch register sets (depth-2, static names only)
  float4 fA0, fA1, fA2, fA3;  int4 lA0, lA1;   // even slabs
  float4 fB0, fB1, fB2, fB3;  int4 lB0, lB1;   // odd slabs

  auto loadA = [&](int s) {
    const int n0 = s * 32 + kseg;
    fA0 = *(const float4*)(row0 + n0);
    fA1 = *(const float4*)(row0 + n0 + 4);
    fA2 = *(const float4*)(row1 + n0);
    fA3 = *(const float4*)(row1 + n0 + 4);
    lA0 = *(const int4*)(labp + n0);
    lA1 = *(const int4*)(labp + n0 + 4);
  };
  auto loadB = [&](int s) {
    const int n0 = s * 32 + kseg;
    fB0 = *(const float4*)(row0 + n0);
    fB1 = *(const float4*)(row0 + n0 + 4);
    fB2 = *(const float4*)(row1 + n0);
    fB3 = *(const float4*)(row1 + n0 + 4);
    lB0 = *(const int4*)(labp + n0);
    lB1 = *(const int4*)(labp + n0 + 4);
  };

  ABits b0v, b1v, av[4];   // derived per slab (av indexed by unrolled kt only)

  auto derive = [&](const float4& f0, const float4& f1, const float4& f2,
                    const float4& f3, const int4& l0, const int4& l1) {
    b0v.u[0] = cvtpk_bf16(f0.x, f0.y);
    b0v.u[1] = cvtpk_bf16(f0.z, f0.w);
    b0v.u[2] = cvtpk_bf16(f1.x, f1.y);
    b0v.u[3] = cvtpk_bf16(f1.z, f1.w);
    b1v.u[0] = cvtpk_bf16(f2.x, f2.y);
    b1v.u[1] = cvtpk_bf16(f2.z, f2.w);
    b1v.u[2] = cvtpk_bf16(f3.x, f3.y);
    b1v.u[3] = cvtpk_bf16(f3.z, f3.w);
#pragma unroll
    for (int kt = 0; kt < 4; ++kt) {
      const int tgt = kt * 16 + crow;
      av[kt].u[0] = (l0.x == tgt ? 0x3F80u : 0u) | (l0.y == tgt ? 0x3F800000u : 0u);
      av[kt].u[1] = (l0.z == tgt ? 0x3F80u : 0u) | (l0.w == tgt ? 0x3F800000u : 0u);
      av[kt].u[2] = (l1.x == tgt ? 0x3F80u : 0u) | (l1.y == tgt ? 0x3F800000u : 0u);
      av[kt].u[3] = (l1.z == tgt ? 0x3F80u : 0u) | (l1.w == tgt ? 0x3F800000u : 0u);
    }
  };

  auto mfma_step = [&]() {
#pragma unroll
    for (int kt = 0; kt < 4; ++kt) {
      acc[kt][0] = __builtin_amdgcn_mfma_f32_16x16x32_bf16(av[kt].v, b0v.v, acc[kt][0], 0, 0, 0);
      acc[kt][1] = __builtin_amdgcn_mfma_f32_16x16x32_bf16(av[kt].v, b1v.v, acc[kt][1], 0, 0, 0);
      accc[kt]   = __builtin_amdgcn_mfma_f32_16x16x32_bf16(av[kt].v, ones.v, accc[kt], 0, 0, 0);
    }
  };

  // ---- prologue ----
  if (w0 < w1) loadA(w0);
  if (w0 + 1 < w1) loadB(w0 + 1);

  // ---- main loop: no barriers, loads for s+2 in flight while s computes ----
  int s = w0;
  while (s < w1) {
    derive(fA0, fA1, fA2, fA3, lA0, lA1);    // waits only its own vmcnt slice
    if (s + 2 < w1) loadA(s + 2);
    __builtin_amdgcn_sched_barrier(0);       // keep loads above the MFMAs
    mfma_step();
    ++s;
    if (s >= w1) break;
    derive(fB0, fB1, fB2, fB3, lB0, lB1);
    if (s + 2 < w1) loadB(s + 2);
    __builtin_amdgcn_sched_barrier(0);
    mfma_step();
    ++s;
  }

  // ---- flush: 4-wave LDS reduce, plain coalesced partial-record store ----
  // D mapping (m89-verified): col = ln&15, row = (ln>>4)*4 + r
#pragma unroll
  for (int kt = 0; kt < 4; ++kt) {
#pragma unroll
    for (int r = 0; r < 4; ++r) {
      const int k = kt * 16 + (ln >> 4) * 4 + r;
      s_part[wv][k * CDIM + crow]      = acc[kt][0][r];
      s_part[wv][k * CDIM + 16 + crow] = acc[kt][1][r];
      if (crow == 0) s_part[wv][KLBL * CDIM + k] = accc[kt][r];
    }
  }
  __syncthreads();

  float* dst = partial + ((size_t)b * CHUNKS + chunk) * REC;
  for (int i = tid; i < REC; i += 256)
    dst[i] = s_part[0][i] + s_part[1][i] + s_part[2][i] + s_part[3][i];
}

// ---------------- Kernel 2: reduce partials -> centers -> hinge loss ------
// grid = BATCH, block = 256. Reads 64 records (540KB, L2-resident).
__global__ __launch_bounds__(256) void loss_kernel(
    const float* __restrict__ partial,  // [B][CHUNKS][REC]
    float* __restrict__ out) {          // zeroed by seg block (0,0)
  const int b = blockIdx.x;
  __shared__ float s_rec[REC];
  __shared__ float s_red[256];

  const float* src = partial + (size_t)b * CHUNKS * REC;
  for (int i = threadIdx.x; i < REC; i += 256) {
    float s = 0.f;
    for (int ch = 0; ch < CHUNKS; ++ch) s += src[(size_t)ch * REC + i];
    s_rec[i] = s;
  }
  __syncthreads();
  for (int i = threadIdx.x; i < KLBL * CDIM; i += 256) {
    const float cnt = fmaxf(s_rec[KLBL * CDIM + (i >> 5)], 1.0f);
    s_rec[i] = s_rec[i] / cnt;          // centers in place
  }
  __syncthreads();

  float acc = 0.f;
  for (int p = threadIdx.x; p < CDIM * CDIM; p += 256) {
    const int i = p >> 5, j = p & 31;
    float gr = 0.f, ni = 0.f, nj = 0.f;
#pragma unroll
    for (int k = 0; k < KLBL; ++k) {
      const float ci = s_rec[k * CDIM + i];
      const float cj = s_rec[k * CDIM + j];
      gr += ci * cj;
      ni += ci * ci;
      nj += cj * cj;
    }
    float sq = fmaxf(ni + nj - 2.f * gr, 0.f);
    const float dist = (sq > 0.f) ? sqrtf(sq) : 0.f;
    const float h = fmaxf(3.0f - dist, 0.f);   // 2*D_DIST = 3.0
    acc += h * h;
  }

  s_red[threadIdx.x] = acc;
  __syncthreads();
  for (int s = 128; s > 0; s >>= 1) {
    if (threadIdx.x < s) s_red[threadIdx.x] += s_red[threadIdx.x + s];
    __syncthreads();
  }
  if (threadIdx.x == 0)
    atomicAdd(out, s_red[0] / (2.0f * (float)KLBL * ((float)KLBL - 1.0f)));
}

// ---------------- launch: exactly 2 graph nodes ----------------
extern "C" void kernel_launch(void* const* d_in, const int* in_sizes, int n_in,
                              void* d_out, int out_size, void* d_ws, size_t ws_size,
                              hipStream_t stream) {
  const float* pred  = (const float*)d_in[0];
  const int*   label = (const int*)d_in[1];
  float* out = (float*)d_out;

  float* partial = (float*)d_ws;   // 512 * 2112 * 4B = 4.33 MB, fully written

  dim3 grid1(CHUNKS, BATCH);
  seg_mfma_kernel<<<grid1, 256, 0, stream>>>(pred, label, partial, out);
  loss_kernel<<<BATCH, 256, 0, stream>>>(partial, out);
}

// Round 12
// 59.969 us; speedup vs baseline: 2.0807x; 1.1800x over previous
//
#include <hip/hip_runtime.h>
#include <stdint.h>

#define BATCH   8
#define CDIM    32
#define KLBL    64
#define NPB     200000               // n per batch (6250 * 32)
#define SLABS   6250                 // 32-n slabs per batch
#define CHUNKS  128                  // 128*8 = 1024 blocks = 4 per CU
#define REC     (KLBL * CDIM + KLBL) // 2112 floats per wave-partial record

typedef __attribute__((ext_vector_type(8))) short bf16x8;
typedef __attribute__((ext_vector_type(4))) float f32x4;

union ABits { uint32_t u[4]; bf16x8 v; };

__device__ __forceinline__ uint32_t cvtpk_bf16(float lo, float hi) {
  uint32_t r;
  asm volatile("v_cvt_pk_bf16_f32 %0, %1, %2" : "=v"(r) : "v"(lo), "v"(hi));
  return r;
}

// ---------------- Kernel 1: barrier-free one-hot MFMA segment sums --------
// grid = (CHUNKS, BATCH), block = 256 (4 waves), 4 blocks/CU via
// __launch_bounds__(256,4) -> 16 waves/CU. Each WAVE owns an exclusive
// n-range; 8 MFMA per 32-n slab. Counts via integer popcount.
// Loop order (R7/R10-verified): derive CONSUMES the prefetch registers into
// b0v/b1v/av FIRST, then the s+2 load may overwrite them, then MFMAs.
__global__ __launch_bounds__(256, 4) void seg_mfma_kernel(
    const float* __restrict__ pred,     // [B][C][N] f32
    const int*   __restrict__ label,    // [B][N] i32
    float* __restrict__ gsums,          // [B][K][C] pre-zeroed
    float* __restrict__ gcounts,        // [B][K]    pre-zeroed
    float* __restrict__ out) {          // scalar; zeroed by block (0,0)
  __shared__ float s_part[4][REC];      // 33.8KB flush buffer

  const int tid = threadIdx.x;
  const int wv = tid >> 6;
  const int ln = tid & 63;
  const int chunk = blockIdx.x, b = blockIdx.y;

  if (chunk == 0 && b == 0 && tid == 0) out[0] = 0.f;  // loss runs after seg

  const int s0 = (int)((long long)chunk * SLABS / CHUNKS);
  const int s1 = (int)((long long)(chunk + 1) * SLABS / CHUNKS);
  const int w0 = s0 + (int)((long long)(s1 - s0) * wv / 4);
  const int w1 = s0 + (int)((long long)(s1 - s0) * (wv + 1) / 4);

  const int crow = ln & 15;          // channel row (and A label-row)
  const int g    = ln >> 4;          // 8-n sub-group within slab
  const int kseg = g * 8;

  const float* row0 = pred + ((size_t)b * CDIM + crow) * NPB;       // c-lo
  const float* row1 = pred + ((size_t)b * CDIM + crow + 16) * NPB;  // c-hi
  const int*   labp = label + (size_t)b * NPB;

  f32x4 acc[4][2];   // [k-tile][c-tile], compile-time indices only
#pragma unroll
  for (int kt = 0; kt < 4; ++kt) {
    acc[kt][0] = (f32x4){0.f, 0.f, 0.f, 0.f};
    acc[kt][1] = (f32x4){0.f, 0.f, 0.f, 0.f};
  }
  uint32_t cnt0 = 0, cnt1 = 0, cnt2 = 0, cnt3 = 0;  // label-count per k-tile

  // two named prefetch register sets (depth-2, static names only)
  float4 fA0, fA1, fA2, fA3;  int4 lA0, lA1;   // even slabs
  float4 fB0, fB1, fB2, fB3;  int4 lB0, lB1;   // odd slabs

  auto loadA = [&](int s) {
    const int n0 = s * 32 + kseg;
    fA0 = *(const float4*)(row0 + n0);
    fA1 = *(const float4*)(row0 + n0 + 4);
    fA2 = *(const float4*)(row1 + n0);
    fA3 = *(const float4*)(row1 + n0 + 4);
    lA0 = *(const int4*)(labp + n0);
    lA1 = *(const int4*)(labp + n0 + 4);
  };
  auto loadB = [&](int s) {
    const int n0 = s * 32 + kseg;
    fB0 = *(const float4*)(row0 + n0);
    fB1 = *(const float4*)(row0 + n0 + 4);
    fB2 = *(const float4*)(row1 + n0);
    fB3 = *(const float4*)(row1 + n0 + 4);
    lB0 = *(const int4*)(labp + n0);
    lB1 = *(const int4*)(labp + n0 + 4);
  };

  ABits b0v, b1v, av[4];   // derived per slab (av indexed by unrolled kt only)

  // derive CONSUMES the f*/l* registers completely (safe to overwrite after)
  auto derive = [&](const float4& f0, const float4& f1, const float4& f2,
                    const float4& f3, const int4& l0, const int4& l1) {
    b0v.u[0] = cvtpk_bf16(f0.x, f0.y);
    b0v.u[1] = cvtpk_bf16(f0.z, f0.w);
    b0v.u[2] = cvtpk_bf16(f1.x, f1.y);
    b0v.u[3] = cvtpk_bf16(f1.z, f1.w);
    b1v.u[0] = cvtpk_bf16(f2.x, f2.y);
    b1v.u[1] = cvtpk_bf16(f2.z, f2.w);
    b1v.u[2] = cvtpk_bf16(f3.x, f3.y);
    b1v.u[3] = cvtpk_bf16(f3.z, f3.w);
#pragma unroll
    for (int kt = 0; kt < 4; ++kt) {
      const int tgt = kt * 16 + crow;
      av[kt].u[0] = (l0.x == tgt ? 0x3F80u : 0u) | (l0.y == tgt ? 0x3F800000u : 0u);
      av[kt].u[1] = (l0.z == tgt ? 0x3F80u : 0u) | (l0.w == tgt ? 0x3F800000u : 0u);
      av[kt].u[2] = (l1.x == tgt ? 0x3F80u : 0u) | (l1.y == tgt ? 0x3F800000u : 0u);
      av[kt].u[3] = (l1.z == tgt ? 0x3F80u : 0u) | (l1.w == tgt ? 0x3F800000u : 0u);
      const uint32_t m =
          (uint32_t)(l0.x == tgt) + (uint32_t)(l0.y == tgt) +
          (uint32_t)(l0.z == tgt) + (uint32_t)(l0.w == tgt) +
          (uint32_t)(l1.x == tgt) + (uint32_t)(l1.y == tgt) +
          (uint32_t)(l1.z == tgt) + (uint32_t)(l1.w == tgt);
      if (kt == 0) cnt0 += m; else if (kt == 1) cnt1 += m;
      else if (kt == 2) cnt2 += m; else cnt3 += m;
    }
  };

  auto mfma_step = [&]() {
#pragma unroll
    for (int kt = 0; kt < 4; ++kt) {
      acc[kt][0] = __builtin_amdgcn_mfma_f32_16x16x32_bf16(av[kt].v, b0v.v, acc[kt][0], 0, 0, 0);
      acc[kt][1] = __builtin_amdgcn_mfma_f32_16x16x32_bf16(av[kt].v, b1v.v, acc[kt][1], 0, 0, 0);
    }
  };

  // ---- prologue ----
  if (w0 < w1) loadA(w0);
  if (w0 + 1 < w1) loadB(w0 + 1);

  // ---- main loop: derive(consume) -> prefetch load -> MFMA ----
  int s = w0;
  while (s < w1) {
    derive(fA0, fA1, fA2, fA3, lA0, lA1);    // consumes A-set fully
    if (s + 2 < w1) loadA(s + 2);            // now safe to overwrite A-set
    __builtin_amdgcn_sched_barrier(0);       // keep loads above the MFMAs
    mfma_step();
    ++s;
    if (s >= w1) break;
    derive(fB0, fB1, fB2, fB3, lB0, lB1);
    if (s + 2 < w1) loadB(s + 2);
    __builtin_amdgcn_sched_barrier(0);
    mfma_step();
    ++s;
  }

  // ---- flush: 4-wave LDS reduce, then global atomics ----
  // D mapping (m89-verified): col = ln&15, row = (ln>>4)*4 + r
  s_part[wv][KLBL * CDIM + ln] = 0.f;   // zero count region (wave-ordered)
#pragma unroll
  for (int kt = 0; kt < 4; ++kt) {
#pragma unroll
    for (int r = 0; r < 4; ++r) {
      const int k = kt * 16 + g * 4 + r;
      s_part[wv][k * CDIM + crow]      = acc[kt][0][r];
      s_part[wv][k * CDIM + 16 + crow] = acc[kt][1][r];
    }
  }
  // counts: lane (crow,g) holds count of label kt*16+crow among its n's
  atomicAdd(&s_part[wv][KLBL * CDIM + 0 * 16 + crow], (float)cnt0);
  atomicAdd(&s_part[wv][KLBL * CDIM + 1 * 16 + crow], (float)cnt1);
  atomicAdd(&s_part[wv][KLBL * CDIM + 2 * 16 + crow], (float)cnt2);
  atomicAdd(&s_part[wv][KLBL * CDIM + 3 * 16 + crow], (float)cnt3);
  __syncthreads();

  float* gs = gsums + (size_t)b * KLBL * CDIM;
  for (int i = tid; i < REC; i += 256) {
    const float v = s_part[0][i] + s_part[1][i] + s_part[2][i] + s_part[3][i];
    if (i < KLBL * CDIM) atomicAdd(&gs[i], v);
    else                 atomicAdd(&gcounts[b * KLBL + (i - KLBL * CDIM)], v);
  }
}

// ---------------- Kernel 2: centers -> pairwise hinge loss ----------------
__global__ __launch_bounds__(256) void loss_kernel(
    const float* __restrict__ gsums,    // [B][K][C]
    const float* __restrict__ gcounts,  // [B][K]
    float* __restrict__ out) {          // zeroed by seg block (0,0)
  const int b = blockIdx.x;
  __shared__ float s_center[KLBL * CDIM];
  __shared__ float s_red[256];

  for (int i = threadIdx.x; i < KLBL * CDIM; i += 256) {
    const float cnt = fmaxf(gcounts[b * KLBL + (i >> 5)], 1.0f);
    s_center[i] = gsums[(size_t)b * KLBL * CDIM + i] / cnt;
  }
  __syncthreads();

  float acc = 0.f;
  for (int p = threadIdx.x; p < CDIM * CDIM; p += 256) {
    const int i = p >> 5, j = p & 31;
    float gr = 0.f, ni = 0.f, nj = 0.f;
#pragma unroll
    for (int k = 0; k < KLBL; ++k) {
      const float ci = s_center[k * CDIM + i];
      const float cj = s_center[k * CDIM + j];
      gr += ci * cj;
      ni += ci * ci;
      nj += cj * cj;
    }
    float sq = fmaxf(ni + nj - 2.f * gr, 0.f);
    const float dist = (sq > 0.f) ? sqrtf(sq) : 0.f;
    const float h = fmaxf(3.0f - dist, 0.f);   // 2*D_DIST = 3.0
    acc += h * h;
  }

  s_red[threadIdx.x] = acc;
  __syncthreads();
  for (int s = 128; s > 0; s >>= 1) {
    if (threadIdx.x < s) s_red[threadIdx.x] += s_red[threadIdx.x + s];
    __syncthreads();
  }
  if (threadIdx.x == 0)
    atomicAdd(out, s_red[0] / (2.0f * (float)KLBL * ((float)KLBL - 1.0f)));
}

// ---------------- launch: 1 memset + 2 kernels ----------------
extern "C" void kernel_launch(void* const* d_in, const int* in_sizes, int n_in,
                              void* d_out, int out_size, void* d_ws, size_t ws_size,
                              hipStream_t stream) {
  const float* pred  = (const float*)d_in[0];
  const int*   label = (const int*)d_in[1];
  float* out = (float*)d_out;

  float* gsums   = (float*)d_ws;                        // B*K*C
  float* gcounts = gsums + (size_t)BATCH * KLBL * CDIM; // B*K

  const size_t accum_bytes =
      (size_t)(BATCH * KLBL * CDIM + BATCH * KLBL) * sizeof(float);
  hipMemsetAsync(d_ws, 0, accum_bytes, stream);

  dim3 grid1(CHUNKS, BATCH);
  seg_mfma_kernel<<<grid1, 256, 0, stream>>>(pred, label, gsums, gcounts, out);
  loss_kernel<<<BATCH, 256, 0, stream>>>(gsums, gcounts, out);
}